// Round 9
// baseline (271.175 us; speedup 1.0000x reference)
//
#include <hip/hip_runtime.h>
#include <hip/hip_bf16.h>

#define NN 100000
#define NE 1600000
#define NT (NN + NE)
#define NBKT 256
#define BSZ 391          // nodes per bucket; 256*391 = 100096 >= NN
#define BCAP 10240       // staging entries per bucket
#define TSH 14           // source-tile shift: tiles of 16384 nodes
#define NPASS 7          // ceil(NN / 16384)

typedef unsigned int u32;
typedef unsigned short u16;

static __device__ __forceinline__ int clampN(int s) {
    return ((unsigned)s < (unsigned)NN) ? s : 0;
}
static __device__ __forceinline__ float2 b2x2(u32 u) {
    float2 r;
    r.x = __uint_as_float((u & 0xffffu) << 16);
    r.y = __uint_as_float(u & 0xffff0000u);
    return r;
}
static __device__ __forceinline__ u16 f2bs(float f) {
    union { __hip_bfloat16 b; u16 u; } cv;
    cv.b = __float2bfloat16(f);
    return cv.u;
}
static __device__ __forceinline__ u32 pack2(float x, float y) {
    return ((u32)f2bs(y) << 16) | (u32)f2bs(x);
}
// leaky-relu then clamp (clamp never active for |e|~O(1); guards exp overflow)
static __device__ __forceinline__ float lrelu_c(float e) {
    e = (e > 0.f) ? e : 0.2f * e;
    return fminf(e, 60.f);
}

#define FMA4(acc, s, v) { acc.x += (s)*(v).x; acc.y += (s)*(v).y; \
                          acc.z += (s)*(v).z; acc.w += (s)*(v).w; }

// ---------------- init: flag/gcur zero, edge-dtype detect, alpha2 vecs ----------------

__global__ void __launch_bounds__(256) k_init(const float* __restrict__ W2,
                                              const float* __restrict__ a2s,
                                              const float* __restrict__ a2d,
                                              const int* __restrict__ ei,
                                              float* __restrict__ va2,
                                              float* __restrict__ vd2,
                                              int* __restrict__ flag,
                                              int* __restrict__ gcur) {
    if (blockIdx.x == 0) {
        if (threadIdx.x == 0) flag[0] = 0;
        __syncthreads();
        int nz = 0;
        for (int i = threadIdx.x; i < 4096; i += 256) nz |= ei[2 * i + 1];
        if (nz) atomicOr(flag, 1);
        if (threadIdx.x < NBKT) gcur[threadIdx.x] = 0;
    } else if (threadIdx.x < 64) {
        int t = threadIdx.x;
        if (t < 32) {
            float a = 0.f;
            for (int c = 0; c < 64; c++) a += W2[t * 64 + c] * a2s[c];
            va2[t] = a;
        } else {
            int k = t - 32;
            float a = 0.f;
            for (int c = 0; c < 64; c++) a += W2[k * 64 + c] * a2d[c];
            vd2[k] = a;
        }
    }
}

// ---------------- CSR build (bucketed counting sort) ----------------

__global__ void __launch_bounds__(256) k_binA(const int* __restrict__ ei,
                                              const int* __restrict__ flag,
                                              int* __restrict__ gcur,
                                              u32* __restrict__ staging) {
    __shared__ int hist[NBKT];
    __shared__ int gbase[NBKT];
    __shared__ int cnt2[NBKT];
    int tid = threadIdx.x;
    if (tid < NBKT) hist[tid] = 0;
    __syncthreads();

    int base = blockIdx.x * 4096;
    int is32 = flag[0];
    int d[16], s[16];
    #pragma unroll
    for (int i = 0; i < 16; i++) {
        int e = base + i * 256 + tid;
        d[i] = -1;
        if (e < NE) {
            int dd, ss;
            if (is32) {
                dd = ei[NE + e];
                ss = ei[e];
            } else {
                dd = ((const int2*)ei)[NE + e].x;
                ss = ((const int2*)ei)[e].x;
            }
            if ((unsigned)dd < (unsigned)NN) { d[i] = dd; s[i] = clampN(ss); }
        } else if (e < NT) {
            d[i] = e - NE; s[i] = e - NE;
        }
        if (d[i] >= 0) atomicAdd(&hist[d[i] / BSZ], 1);
    }
    __syncthreads();
    if (tid < NBKT) {
        int c = hist[tid];
        gbase[tid] = c ? atomicAdd(&gcur[tid], c) : 0;
        cnt2[tid] = 0;
    }
    __syncthreads();
    #pragma unroll
    for (int i = 0; i < 16; i++) {
        if (d[i] >= 0) {
            int b = d[i] / BSZ;
            int pos = gbase[b] + atomicAdd(&cnt2[b], 1);
            if (pos < BCAP)
                staging[(size_t)b * BCAP + pos] =
                    ((unsigned)(d[i] - b * BSZ) << 17) | (unsigned)s[i];
        }
    }
}

// per-bucket degree histogram + bucket-local exclusive scan; packs xpb PRE-SCALED by dinv
__global__ void __launch_bounds__(256) k_histscan(const u32* __restrict__ staging,
                                                  const int* __restrict__ gcur,
                                                  const float* __restrict__ x,
                                                  u32* __restrict__ xpb,
                                                  int* __restrict__ rowptr,
                                                  int* __restrict__ deg,
                                                  int* __restrict__ part) {
    __shared__ int h[512];
    __shared__ int sm[256];
    int b = blockIdx.x, tid = threadIdx.x;
    h[tid] = 0; h[tid + 256] = 0;
    __syncthreads();
    int cnt = min(gcur[b], BCAP);
    const u32* st = staging + (size_t)b * BCAP;
    for (int i = tid; i < cnt; i += 256)
        atomicAdd(&h[st[i] >> 17], 1);
    __syncthreads();
    int h0 = h[2 * tid], h1 = h[2 * tid + 1];
    int pair = h0 + h1;
    sm[tid] = pair;
    __syncthreads();
    for (int off = 1; off < 256; off <<= 1) {
        int t = (tid >= off) ? sm[tid - off] : 0;
        __syncthreads();
        sm[tid] += t;
        __syncthreads();
    }
    int excl = sm[tid] - pair;                   // exclusive over pairs
    int g0 = b * BSZ + 2 * tid;
    if (2 * tid < BSZ && g0 < NN) { rowptr[g0] = excl; deg[g0] = h0; }
    int g1 = g0 + 1;
    if (2 * tid + 1 < BSZ && g1 < NN) { rowptr[g1] = excl + h0; deg[g1] = h1; }
    if (tid == 255) part[b] = sm[255];
    __syncthreads();                             // h[] stable for pack below

    // xpb pack for THIS bucket's nodes, pre-scaled by dinv[node] (h[l] = degree).
    for (int i = tid; i < BSZ * 4; i += 256) {
        int l = i >> 2;
        int g = b * BSZ + l;
        if (g < NN) {
            int c2 = i & 3;
            int d = h[l];
            float w = rsqrtf((float)(d > 0 ? d : 1));
            float f0 = x[g * 7 + 2 * c2] * w;
            float f1 = (2 * c2 + 1 < 7) ? x[g * 7 + 2 * c2 + 1] * w : 0.f;
            xpb[(size_t)g * 4 + c2] = pack2(f0, f1);
        }
    }
}

// finalize rowptr/dinv + scatter into col, SOURCE-TILE-ORDERED (7 filtered passes):
// cols within each row end up sorted by src>>TSH, so all gather kernels sweep the
// source arrays through a ~2MB moving window -> L2-resident row reuse.
__global__ void __launch_bounds__(256) k_scat(const u32* __restrict__ staging,
                                              const int* __restrict__ gcur,
                                              const int* __restrict__ part,
                                              int* __restrict__ rowptr,
                                              const int* __restrict__ deg,
                                              float* __restrict__ dinv,
                                              int* __restrict__ col) {
    __shared__ int sm[256];
    __shared__ int cur[BSZ];
    int b = blockIdx.x, tid = threadIdx.x;
    int v = part[tid];
    sm[tid] = v;
    __syncthreads();
    for (int off = 1; off < 256; off <<= 1) {
        int t = (tid >= off) ? sm[tid - off] : 0;
        __syncthreads();
        sm[tid] += t;
        __syncthreads();
    }
    int pb = (b > 0) ? sm[b - 1] : 0;            // exclusive bucket prefix
    if (b == 0 && tid == 0) rowptr[NN] = NT;
    for (int l = tid; l < BSZ; l += 256) {
        int g = b * BSZ + l;
        if (g < NN) {
            int r = rowptr[g] + pb;
            rowptr[g] = r;
            cur[l] = r;
            int d = deg[g];
            dinv[g] = rsqrtf((float)(d > 0 ? d : 1));
        } else cur[l] = 0;
    }
    __syncthreads();
    int cnt = min(gcur[b], BCAP);
    const u32* st = staging + (size_t)b * BCAP;
    for (int pass = 0; pass < NPASS; pass++) {
        for (int i = tid; i < cnt; i += 256) {
            u32 w = st[i];
            int s = w & 0x1FFFF;
            if ((s >> TSH) != pass) continue;
            int l = w >> 17;
            int p = atomicAdd(&cur[l], 1);
            if ((unsigned)p < (unsigned)NT) col[p] = s;
        }
        __syncthreads();             // keep tile ordering clean across passes
    }
}

// ---------------- layer 1 fused: GCN agg (pre-scaled bf16 xp) -> LDS -> dense 7->32 + alpha2 ----------------
// 64 nodes/block; 4 lanes/node = 2 edge-slots x 2 chunks. Inner loop: col -> xpb add only.

__global__ void __launch_bounds__(256) k_l1(const u32* __restrict__ xpb,
                                            const int* __restrict__ rowptr,
                                            const int* __restrict__ col,
                                            const float* __restrict__ dinv,
                                            const float* __restrict__ W1,
                                            const float* __restrict__ b1,
                                            const float* __restrict__ va2,
                                            const float* __restrict__ vd2,
                                            u32* __restrict__ O1b,
                                            float* __restrict__ as_,
                                            float* __restrict__ ad_) {
    __shared__ float sW1[7 * 32];
    __shared__ float sb1[32], sva[32], svd[32];
    __shared__ float sT1[64 * 8];
    if (threadIdx.x < 224) sW1[threadIdx.x] = W1[threadIdx.x];
    else {
        int c = threadIdx.x - 224;
        sb1[c] = b1[c]; sva[c] = va2[c]; svd[c] = vd2[c];
    }
    __syncthreads();                 // weights staged; gather/dense are wave-local

    int node_l = threadIdx.x >> 2;
    int lane = threadIdx.x & 3;
    int slot = lane >> 1;            // 2 edge slots
    int ck = lane & 1;               // chunk: words 2ck,2ck+1 -> ch 4ck..4ck+3
    int n = blockIdx.x * 64 + node_l;
    if (n >= NN) return;
    {
        int beg = rowptr[n], end = rowptr[n + 1];
        float a0 = 0.f, a1 = 0.f, a2 = 0.f, a3 = 0.f;
        #pragma unroll 4
        for (int e = beg + slot; e < end; e += 2) {
            int s = clampN(col[e]);
            uint2 u = *(const uint2*)(xpb + (size_t)s * 4 + ck * 2);
            float2 f0 = b2x2(u.x), f1 = b2x2(u.y);
            a0 += f0.x; a1 += f0.y; a2 += f1.x; a3 += f1.y;
        }
        // merge slots (lane ^ 2 within node quad)
        a0 += __shfl_xor(a0, 2, 4); a1 += __shfl_xor(a1, 2, 4);
        a2 += __shfl_xor(a2, 2, 4); a3 += __shfl_xor(a3, 2, 4);
        if (slot == 0) {
            float dn = dinv[n];
            float4 o = {a0 * dn, a1 * dn, a2 * dn, a3 * dn};
            *(float4*)&sT1[node_l * 8 + ck * 4] = o;
        }
    }
    __builtin_amdgcn_wave_barrier();
    int c8 = lane * 8;
    float4 aA = {0,0,0,0}, aB = {0,0,0,0};
    #pragma unroll
    for (int k = 0; k < 7; k++) {
        float t = sT1[node_l * 8 + k];
        float4 wva = *(const float4*)&sW1[k * 32 + c8];
        float4 wvb = *(const float4*)&sW1[k * 32 + c8 + 4];
        FMA4(aA, t, wva);
        FMA4(aB, t, wvb);
    }
    float o0 = fmaxf(aA.x + sb1[c8], 0.f);
    float o1 = fmaxf(aA.y + sb1[c8 + 1], 0.f);
    float o2 = fmaxf(aA.z + sb1[c8 + 2], 0.f);
    float o3 = fmaxf(aA.w + sb1[c8 + 3], 0.f);
    float o4 = fmaxf(aB.x + sb1[c8 + 4], 0.f);
    float o5 = fmaxf(aB.y + sb1[c8 + 5], 0.f);
    float o6 = fmaxf(aB.z + sb1[c8 + 6], 0.f);
    float o7 = fmaxf(aB.w + sb1[c8 + 7], 0.f);
    uint4 pk = {pack2(o0, o1), pack2(o2, o3), pack2(o4, o5), pack2(o6, o7)};
    *(uint4*)(O1b + (size_t)n * 16 + lane * 4) = pk;
    float vs = o0 * sva[c8] + o1 * sva[c8 + 1] + o2 * sva[c8 + 2] + o3 * sva[c8 + 3]
             + o4 * sva[c8 + 4] + o5 * sva[c8 + 5] + o6 * sva[c8 + 6] + o7 * sva[c8 + 7];
    float vd = o0 * svd[c8] + o1 * svd[c8 + 1] + o2 * svd[c8 + 2] + o3 * svd[c8 + 3]
             + o4 * svd[c8 + 4] + o5 * svd[c8 + 5] + o6 * svd[c8 + 6] + o7 * svd[c8 + 7];
    vs += __shfl_xor(vs, 1, 4); vs += __shfl_xor(vs, 2, 4);
    vd += __shfl_xor(vd, 1, 4); vd += __shfl_xor(vd, 2, 4);
    if (lane == 0) { as_[n] = vs; ad_[n] = vd; }
}

// ---------------- layer 2 fused: GAT single-pass agg -> LDS -> dense 32->64 ----------------
// 32 nodes/block; 8 lanes/node = 2 edge-slots x 4 chunks (8 ch each). Wave-synchronous.

__global__ void __launch_bounds__(256) k_l2(const u32* __restrict__ O1b,
                                            const float* __restrict__ as_,
                                            const float* __restrict__ ad_,
                                            const int* __restrict__ rowptr,
                                            const int* __restrict__ col,
                                            const float* __restrict__ W2,
                                            const float* __restrict__ b2,
                                            const float* __restrict__ dinv,
                                            u32* __restrict__ O2b) {
    __shared__ float sW2[32 * 64];    // 8 KB
    __shared__ float sT2[32 * 36];    // stride 36
    __shared__ float sb2[64];
    {
        const float4* g = (const float4*)W2;
        float4* s4 = (float4*)sW2;
        s4[threadIdx.x] = g[threadIdx.x];
        s4[threadIdx.x + 256] = g[threadIdx.x + 256];
    }
    if (threadIdx.x < 64) sb2[threadIdx.x] = b2[threadIdx.x];
    __syncthreads();                 // weights staged; rest is wave-local

    int node_l = threadIdx.x >> 3;
    int l8 = threadIdx.x & 7;
    int slot = l8 >> 2;              // 2 edge slots
    int ck = l8 & 3;                 // chunk: words 4ck..4ck+3 -> ch 8ck..8ck+7
    int n = blockIdx.x * 32 + node_l;            // 3125*32 = NN exact
    {
        int beg = rowptr[n], end = rowptr[n + 1];
        float adn = ad_[n];
        float den = 0.f;
        float a0=0.f,a1=0.f,a2=0.f,a3=0.f,a4=0.f,a5=0.f,a6=0.f,a7=0.f;
        #pragma unroll 2
        for (int e = beg + slot; e < end; e += 2) {
            int s = clampN(col[e]);
            float p = __expf(lrelu_c(as_[s] + adn));
            den += p;
            uint4 w = *(const uint4*)(O1b + (size_t)s * 16 + ck * 4);
            float2 f0 = b2x2(w.x), f1 = b2x2(w.y), f2 = b2x2(w.z), f3 = b2x2(w.w);
            a0 += p * f0.x; a1 += p * f0.y; a2 += p * f1.x; a3 += p * f1.y;
            a4 += p * f2.x; a5 += p * f2.y; a6 += p * f3.x; a7 += p * f3.y;
        }
        // merge slots (lane ^ 4 within node octet)
        den += __shfl_xor(den, 4, 8);
        a0 += __shfl_xor(a0, 4, 8); a1 += __shfl_xor(a1, 4, 8);
        a2 += __shfl_xor(a2, 4, 8); a3 += __shfl_xor(a3, 4, 8);
        a4 += __shfl_xor(a4, 4, 8); a5 += __shfl_xor(a5, 4, 8);
        a6 += __shfl_xor(a6, 4, 8); a7 += __shfl_xor(a7, 4, 8);
        if (slot == 0) {
            float inv = 1.0f / (den + 1e-16f);
            float4 oA = {a0 * inv, a1 * inv, a2 * inv, a3 * inv};
            float4 oB = {a4 * inv, a5 * inv, a6 * inv, a7 * inv};
            float* dst = &sT2[node_l * 36 + ck * 8];
            *(float4*)dst = oA;
            *(float4*)(dst + 4) = oB;
        }
    }
    __builtin_amdgcn_wave_barrier();

    int grp = threadIdx.x >> 4;      // 16 groups
    int l = threadIdx.x & 15;
    int c4 = l * 4;
    int lbase = grp * 2;             // 2 nodes per group

    float4 acc0 = {0,0,0,0}, acc1 = {0,0,0,0};
    #pragma unroll
    for (int k4 = 0; k4 < 8; k4++) {
        float4 t0 = *(const float4*)&sT2[(lbase + 0) * 36 + 4 * k4];
        float4 t1 = *(const float4*)&sT2[(lbase + 1) * 36 + 4 * k4];
        #pragma unroll
        for (int j = 0; j < 4; j++) {
            float4 wv = *(const float4*)&sW2[(4 * k4 + j) * 64 + c4];
            FMA4(acc0, ((const float*)&t0)[j], wv);
            FMA4(acc1, ((const float*)&t1)[j], wv);
        }
    }
    float4 bb = *(const float4*)&sb2[c4];
    int n0 = blockIdx.x * 32 + lbase;
    float d0 = dinv[n0], d1 = dinv[n0 + 1];
    {
        float o0 = fmaxf(acc0.x + bb.x, 0.f) * d0;
        float o1 = fmaxf(acc0.y + bb.y, 0.f) * d0;
        float o2 = fmaxf(acc0.z + bb.z, 0.f) * d0;
        float o3 = fmaxf(acc0.w + bb.w, 0.f) * d0;
        uint2 pk = {pack2(o0, o1), pack2(o2, o3)};
        *(uint2*)(O2b + (size_t)n0 * 32 + l * 2) = pk;
    }
    {
        float o0 = fmaxf(acc1.x + bb.x, 0.f) * d1;
        float o1 = fmaxf(acc1.y + bb.y, 0.f) * d1;
        float o2 = fmaxf(acc1.z + bb.z, 0.f) * d1;
        float o3 = fmaxf(acc1.w + bb.w, 0.f) * d1;
        uint2 pk = {pack2(o0, o1), pack2(o2, o3)};
        *(uint2*)(O2b + (size_t)(n0 + 1) * 32 + l * 2) = pk;
    }
}

// ---------------- layer 3 FUSED: GCN agg over bf16 O2b -> LDS -> W3 -> relu -> W4 ----------------
// R1 structure (best measured): 64 nodes/block, 512 threads, wave-synchronous, sT3 stride 68.

__global__ void __launch_bounds__(512) k_l3(const u32* __restrict__ O2b,
                                            const int* __restrict__ rowptr,
                                            const int* __restrict__ col,
                                            const float* __restrict__ dinv,
                                            const float* __restrict__ W3,
                                            const float* __restrict__ b3,
                                            const float* __restrict__ W4,
                                            const float* __restrict__ av4s,
                                            const float* __restrict__ av4d,
                                            float4* __restrict__ h4as,
                                            float* __restrict__ ad_) {
    __shared__ float sW3[64 * 128];   // 32 KB
    __shared__ float sT3[64 * 68];    // 17 KB, stride 68
    __shared__ float sW4[128 * 2];
    __shared__ float sb3[128];

    {
        const float4* g = (const float4*)W3;
        float4* s4 = (float4*)sW3;
        #pragma unroll
        for (int i = 0; i < 4; i++) s4[threadIdx.x + 512 * i] = g[threadIdx.x + 512 * i];
    }
    if (threadIdx.x < 128) {
        sb3[threadIdx.x] = b3[threadIdx.x];
        sW4[2 * threadIdx.x] = W4[2 * threadIdx.x];
        sW4[2 * threadIdx.x + 1] = W4[2 * threadIdx.x + 1];
    }
    __syncthreads();                  // weights staged; gather/dense are wave-local

    int w = threadIdx.x >> 6;         // wave id 0..7
    int l = threadIdx.x & 63;
    int row = w * 8 + (l >> 3);       // block-local row 0..63
    int cl = l & 7;                   // channel-owner lane
    int n = blockIdx.x * 64 + row;
    if (n >= NN) return;

    // ---- gather: 8 lanes/node, lane cl owns channels cl*8..cl*8+7 ----
    {
        int beg = rowptr[n], end = rowptr[n + 1];
        float4 accA = {0,0,0,0}, accB = {0,0,0,0};
        #pragma unroll 4
        for (int e = beg; e < end; e++) {
            int s = clampN(col[e]);
            uint4 wd = *(const uint4*)(O2b + (size_t)s * 32 + cl * 4);
            float2 f0 = b2x2(wd.x), f1 = b2x2(wd.y), f2 = b2x2(wd.z), f3 = b2x2(wd.w);
            accA.x += f0.x; accA.y += f0.y; accA.z += f1.x; accA.w += f1.y;
            accB.x += f2.x; accB.y += f2.y; accB.z += f3.x; accB.w += f3.y;
        }
        float dn = dinv[n];
        accA.x *= dn; accA.y *= dn; accA.z *= dn; accA.w *= dn;
        accB.x *= dn; accB.y *= dn; accB.z *= dn; accB.w *= dn;
        float* dst = &sT3[row * 68 + cl * 8];
        *(float4*)dst = accA;
        *(float4*)(dst + 4) = accB;
    }
    __builtin_amdgcn_wave_barrier();

    // ---- dense: same wave consumes its own rows; lane cl owns quads {4cl,+32,+64,+96} ----
    const float* trow = &sT3[row * 68];
    float4 acc0 = {0,0,0,0}, acc1 = {0,0,0,0}, acc2 = {0,0,0,0}, acc3 = {0,0,0,0};
    #pragma unroll 4
    for (int k4 = 0; k4 < 16; k4++) {
        float4 t4 = *(const float4*)&trow[k4 * 4];
        #pragma unroll
        for (int j = 0; j < 4; j++) {
            float tj = ((const float*)&t4)[j];
            const float* wr = &sW3[(4 * k4 + j) * 128 + 4 * cl];
            float4 w0 = *(const float4*)&wr[0];
            float4 w1 = *(const float4*)&wr[32];
            float4 w2 = *(const float4*)&wr[64];
            float4 w3v = *(const float4*)&wr[96];
            FMA4(acc0, tj, w0);
            FMA4(acc1, tj, w1);
            FMA4(acc2, tj, w2);
            FMA4(acc3, tj, w3v);
        }
    }

    float av4s0 = av4s[0], av4s1 = av4s[1];
    float av4d0 = av4d[0], av4d1 = av4d[1];
    float p0 = 0.f, p1 = 0.f;
    #pragma unroll
    for (int q = 0; q < 4; q++) {
        float4 a = (q == 0) ? acc0 : (q == 1) ? acc1 : (q == 2) ? acc2 : acc3;
        int c = 4 * cl + 32 * q;
        float4 bb = *(const float4*)&sb3[c];
        a.x = fmaxf(a.x + bb.x, 0.f);
        a.y = fmaxf(a.y + bb.y, 0.f);
        a.z = fmaxf(a.z + bb.z, 0.f);
        a.w = fmaxf(a.w + bb.w, 0.f);
        p0 += a.x * sW4[2 * c]     + a.y * sW4[2 * (c + 1)]
            + a.z * sW4[2 * (c + 2)] + a.w * sW4[2 * (c + 3)];
        p1 += a.x * sW4[2 * c + 1]     + a.y * sW4[2 * (c + 1) + 1]
            + a.z * sW4[2 * (c + 2) + 1] + a.w * sW4[2 * (c + 3) + 1];
    }
    p0 += __shfl_xor(p0, 1, 8); p0 += __shfl_xor(p0, 2, 8); p0 += __shfl_xor(p0, 4, 8);
    p1 += __shfl_xor(p1, 1, 8); p1 += __shfl_xor(p1, 2, 8); p1 += __shfl_xor(p1, 4, 8);
    if (cl == 0) {
        float asv = p0 * av4s0 + p1 * av4s1;
        float4 pk = {p0, p1, asv, 0.f};
        h4as[n] = pk;
        ad_[n] = p0 * av4d0 + p1 * av4d1;
    }
}

// ---------------- final GAT (2ch) + log_softmax, single-pass, 4 lanes/node ----------------

__global__ void k_final(const float4* __restrict__ h4as,
                        const float* __restrict__ ad_, const int* __restrict__ rowptr,
                        const int* __restrict__ col, const float* __restrict__ b,
                        float* __restrict__ out) {
    int gid = blockIdx.x * 256 + threadIdx.x;  // NN*4
    int n = gid >> 2;
    if (n >= NN) return;
    int lsub = gid & 3;
    int beg = rowptr[n], end = rowptr[n + 1];
    float adn = ad_[n];
    float den = 0.f, a0 = 0.f, a1 = 0.f;
    for (int e = beg + lsub; e < end; e += 4) {
        int s = clampN(col[e]);
        float4 h = h4as[s];
        float p = __expf(lrelu_c(h.z + adn));
        den += p;
        a0 += p * h.x;
        a1 += p * h.y;
    }
    den += __shfl_xor(den, 1, 4); den += __shfl_xor(den, 2, 4);
    a0  += __shfl_xor(a0, 1, 4);  a0  += __shfl_xor(a0, 2, 4);
    a1  += __shfl_xor(a1, 1, 4);  a1  += __shfl_xor(a1, 2, 4);
    if (lsub == 0) {
        float inv = 1.0f / (den + 1e-16f);
        float v0 = a0 * inv + b[0];
        float v1 = a1 * inv + b[1];
        float mx = fmaxf(v0, v1);
        float lse = mx + logf(__expf(v0 - mx) + __expf(v1 - mx));
        float2 o = {v0 - lse, v1 - lse};
        *(float2*)(out + n * 2) = o;
    }
}

__global__ void k_sentinel(float* __restrict__ out, float v) {
    int i = blockIdx.x * 256 + threadIdx.x;
    if (i < NN * 2) out[i] = v;
}

// ---------------- launch ----------------

extern "C" void kernel_launch(void* const* d_in, const int* in_sizes, int n_in,
                              void* d_out, int out_size, void* d_ws, size_t ws_size,
                              hipStream_t stream) {
    const float* x    = (const float*)d_in[0];
    const int* ei     = (const int*)d_in[1];
    const float* W1   = (const float*)d_in[2];
    const float* b1   = (const float*)d_in[3];
    const float* W2   = (const float*)d_in[4];
    const float* a2s  = (const float*)d_in[5];
    const float* a2d  = (const float*)d_in[6];
    const float* b2   = (const float*)d_in[7];
    const float* W3   = (const float*)d_in[8];
    const float* b3   = (const float*)d_in[9];
    const float* W4   = (const float*)d_in[10];
    const float* a4s  = (const float*)d_in[11];
    const float* a4d  = (const float*)d_in[12];
    const float* b4   = (const float*)d_in[13];
    float* out = (float*)d_out;

    char* base = (char*)d_ws;
    size_t off = 0;
    auto alloc = [&](size_t bytes) {
        char* q = base + off;
        off += (bytes + 255) & ~(size_t)255;
        return q;
    };
    u32* xpb     = (u32*)alloc((size_t)NN * 4 * 4);      // 1.6 MB
    u32* O1b     = (u32*)alloc((size_t)NN * 16 * 4);     // 6.4 MB
    u32* O2b     = (u32*)alloc((size_t)NN * 32 * 4);     // 12.8 MB
    u32* staging = (u32*)alloc((size_t)NBKT * BCAP * 4); // 10.5 MB
    int* col     = (int*)alloc((size_t)NT * 4);          // 6.8 MB
    int* rowptr  = (int*)alloc((size_t)(NN + 1) * 4);
    int* deg     = (int*)alloc((size_t)NN * 4);
    float* dinv  = (float*)alloc((size_t)NN * 4);
    float* as_   = (float*)alloc((size_t)NN * 4);
    float* ad_   = (float*)alloc((size_t)NN * 4);
    float4* h4as = (float4*)alloc((size_t)NN * 16);
    int* part    = (int*)alloc(512 * 4);
    int* flag    = (int*)alloc(256);
    int* gcur    = (int*)alloc(NBKT * 4);
    float* va2   = (float*)alloc(32 * 4);
    float* vd2   = (float*)alloc(32 * 4);

    float code = 0.f;
    if (off > ws_size)            code = 1000.f + (float)(ws_size >> 20);
    else if (n_in != 14)          code = 2000.f + 10.f * (float)n_in;
    else if (out_size != NN * 2)  code = 3400.f;
    if (code != 0.f) {
        k_sentinel<<<(NN * 2 + 255) / 256, 256, 0, stream>>>(out, code);
        return;
    }

    const int NTILE = (NT + 4095) / 4096;

    // CSR build: init -> bin -> hist+localscan(+prescaled xpb pack) -> finalize+tile-ordered scatter
    k_init<<<2, 256, 0, stream>>>(W2, a2s, a2d, ei, va2, vd2, flag, gcur);
    k_binA<<<NTILE, 256, 0, stream>>>(ei, flag, gcur, staging);
    k_histscan<<<NBKT, 256, 0, stream>>>(staging, gcur, x, xpb, rowptr, deg, part);
    k_scat<<<NBKT, 256, 0, stream>>>(staging, gcur, part, rowptr, deg, dinv, col);

    // layer 1 fused: agg(pre-scaled bf16 xp) + dense 7->32 + alpha2
    k_l1<<<(NN + 63) / 64, 256, 0, stream>>>(xpb, rowptr, col, dinv,
                                             W1, b1, va2, vd2, O1b, as_, ad_);
    // layer 2 fused: GAT agg + dense 32->64
    k_l2<<<NN / 32, 256, 0, stream>>>(O1b, as_, ad_, rowptr, col,
                                      W2, b2, dinv, O2b);
    // layer 3 fused: GCN agg + dense 64->128 -> relu -> W4 (R1 best structure)
    k_l3<<<(NN + 63) / 64, 512, 0, stream>>>(O2b, rowptr, col, dinv,
                                             W3, b3, W4, a4s, a4d, h4as, ad_);
    // layer 4 agg + log_softmax
    k_final<<<NN * 4 / 256 + 1, 256, 0, stream>>>(h4as, ad_, rowptr, col, b4, out);
}

// Round 10
// 241.619 us; speedup vs baseline: 1.1223x; 1.1223x over previous
//
#include <hip/hip_runtime.h>
#include <hip/hip_bf16.h>

#define NN 100000
#define NE 1600000
#define NT (NN + NE)
#define NBKT 256
#define BSZ 391          // nodes per bucket; 256*391 = 100096 >= NN
#define BCAP 10240       // staging entries per bucket

typedef unsigned int u32;
typedef unsigned short u16;

static __device__ __forceinline__ int clampN(int s) {
    return ((unsigned)s < (unsigned)NN) ? s : 0;
}
static __device__ __forceinline__ float2 b2x2(u32 u) {
    float2 r;
    r.x = __uint_as_float((u & 0xffffu) << 16);
    r.y = __uint_as_float(u & 0xffff0000u);
    return r;
}
static __device__ __forceinline__ u16 f2bs(float f) {
    union { __hip_bfloat16 b; u16 u; } cv;
    cv.b = __float2bfloat16(f);
    return cv.u;
}
static __device__ __forceinline__ u32 pack2(float x, float y) {
    return ((u32)f2bs(y) << 16) | (u32)f2bs(x);
}
// leaky-relu then clamp (clamp never active for |e|~O(1); guards exp overflow)
static __device__ __forceinline__ float lrelu_c(float e) {
    e = (e > 0.f) ? e : 0.2f * e;
    return fminf(e, 60.f);
}

#define FMA4(acc, s, v) { acc.x += (s)*(v).x; acc.y += (s)*(v).y; \
                          acc.z += (s)*(v).z; acc.w += (s)*(v).w; }

// ---------------- init: flag/gcur zero, edge-dtype detect, alpha2 vecs ----------------

__global__ void __launch_bounds__(256) k_init(const float* __restrict__ W2,
                                              const float* __restrict__ a2s,
                                              const float* __restrict__ a2d,
                                              const int* __restrict__ ei,
                                              float* __restrict__ va2,
                                              float* __restrict__ vd2,
                                              int* __restrict__ flag,
                                              int* __restrict__ gcur) {
    if (blockIdx.x == 0) {
        if (threadIdx.x == 0) flag[0] = 0;
        __syncthreads();
        int nz = 0;
        for (int i = threadIdx.x; i < 4096; i += 256) nz |= ei[2 * i + 1];
        if (nz) atomicOr(flag, 1);
        if (threadIdx.x < NBKT) gcur[threadIdx.x] = 0;
    } else if (threadIdx.x < 64) {
        int t = threadIdx.x;
        if (t < 32) {
            float a = 0.f;
            for (int c = 0; c < 64; c++) a += W2[t * 64 + c] * a2s[c];
            va2[t] = a;
        } else {
            int k = t - 32;
            float a = 0.f;
            for (int c = 0; c < 64; c++) a += W2[k * 64 + c] * a2d[c];
            vd2[k] = a;
        }
    }
}

// ---------------- CSR build (bucketed counting sort) ----------------

__global__ void __launch_bounds__(256) k_binA(const int* __restrict__ ei,
                                              const int* __restrict__ flag,
                                              int* __restrict__ gcur,
                                              u32* __restrict__ staging) {
    __shared__ int hist[NBKT];
    __shared__ int gbase[NBKT];
    __shared__ int cnt2[NBKT];
    int tid = threadIdx.x;
    if (tid < NBKT) hist[tid] = 0;
    __syncthreads();

    int base = blockIdx.x * 4096;
    int is32 = flag[0];
    int d[16], s[16];
    #pragma unroll
    for (int i = 0; i < 16; i++) {
        int e = base + i * 256 + tid;
        d[i] = -1;
        if (e < NE) {
            int dd, ss;
            if (is32) {
                dd = ei[NE + e];
                ss = ei[e];
            } else {
                dd = ((const int2*)ei)[NE + e].x;
                ss = ((const int2*)ei)[e].x;
            }
            if ((unsigned)dd < (unsigned)NN) { d[i] = dd; s[i] = clampN(ss); }
        } else if (e < NT) {
            d[i] = e - NE; s[i] = e - NE;
        }
        if (d[i] >= 0) atomicAdd(&hist[d[i] / BSZ], 1);
    }
    __syncthreads();
    if (tid < NBKT) {
        int c = hist[tid];
        gbase[tid] = c ? atomicAdd(&gcur[tid], c) : 0;
        cnt2[tid] = 0;
    }
    __syncthreads();
    #pragma unroll
    for (int i = 0; i < 16; i++) {
        if (d[i] >= 0) {
            int b = d[i] / BSZ;
            int pos = gbase[b] + atomicAdd(&cnt2[b], 1);
            if (pos < BCAP)
                staging[(size_t)b * BCAP + pos] =
                    ((unsigned)(d[i] - b * BSZ) << 17) | (unsigned)s[i];
        }
    }
}

// per-bucket degree histogram + bucket-local exclusive scan; packs xpb PRE-SCALED by dinv
__global__ void __launch_bounds__(256) k_histscan(const u32* __restrict__ staging,
                                                  const int* __restrict__ gcur,
                                                  const float* __restrict__ x,
                                                  u32* __restrict__ xpb,
                                                  int* __restrict__ rowptr,
                                                  int* __restrict__ deg,
                                                  int* __restrict__ part) {
    __shared__ int h[512];
    __shared__ int sm[256];
    int b = blockIdx.x, tid = threadIdx.x;
    h[tid] = 0; h[tid + 256] = 0;
    __syncthreads();
    int cnt = min(gcur[b], BCAP);
    const u32* st = staging + (size_t)b * BCAP;
    for (int i = tid; i < cnt; i += 256)
        atomicAdd(&h[st[i] >> 17], 1);
    __syncthreads();
    int h0 = h[2 * tid], h1 = h[2 * tid + 1];
    int pair = h0 + h1;
    sm[tid] = pair;
    __syncthreads();
    for (int off = 1; off < 256; off <<= 1) {
        int t = (tid >= off) ? sm[tid - off] : 0;
        __syncthreads();
        sm[tid] += t;
        __syncthreads();
    }
    int excl = sm[tid] - pair;                   // exclusive over pairs
    int g0 = b * BSZ + 2 * tid;
    if (2 * tid < BSZ && g0 < NN) { rowptr[g0] = excl; deg[g0] = h0; }
    int g1 = g0 + 1;
    if (2 * tid + 1 < BSZ && g1 < NN) { rowptr[g1] = excl + h0; deg[g1] = h1; }
    if (tid == 255) part[b] = sm[255];
    __syncthreads();                             // h[] stable for pack below

    // xpb pack for THIS bucket's nodes, pre-scaled by dinv[node] (h[l] = degree).
    for (int i = tid; i < BSZ * 4; i += 256) {
        int l = i >> 2;
        int g = b * BSZ + l;
        if (g < NN) {
            int c2 = i & 3;
            int d = h[l];
            float w = rsqrtf((float)(d > 0 ? d : 1));
            float f0 = x[g * 7 + 2 * c2] * w;
            float f1 = (2 * c2 + 1 < 7) ? x[g * 7 + 2 * c2 + 1] * w : 0.f;
            xpb[(size_t)g * 4 + c2] = pack2(f0, f1);
        }
    }
}

// finalize rowptr/dinv + scatter into col; bucket prefix computed by local scan of part[]
__global__ void __launch_bounds__(256) k_scat(const u32* __restrict__ staging,
                                              const int* __restrict__ gcur,
                                              const int* __restrict__ part,
                                              int* __restrict__ rowptr,
                                              const int* __restrict__ deg,
                                              float* __restrict__ dinv,
                                              int* __restrict__ col) {
    __shared__ int sm[256];
    __shared__ int cur[BSZ];
    int b = blockIdx.x, tid = threadIdx.x;
    int v = part[tid];
    sm[tid] = v;
    __syncthreads();
    for (int off = 1; off < 256; off <<= 1) {
        int t = (tid >= off) ? sm[tid - off] : 0;
        __syncthreads();
        sm[tid] += t;
        __syncthreads();
    }
    int pb = (b > 0) ? sm[b - 1] : 0;            // exclusive bucket prefix
    if (b == 0 && tid == 0) rowptr[NN] = NT;
    for (int l = tid; l < BSZ; l += 256) {
        int g = b * BSZ + l;
        if (g < NN) {
            int r = rowptr[g] + pb;
            rowptr[g] = r;
            cur[l] = r;
            int d = deg[g];
            dinv[g] = rsqrtf((float)(d > 0 ? d : 1));
        } else cur[l] = 0;
    }
    __syncthreads();
    int cnt = min(gcur[b], BCAP);
    const u32* st = staging + (size_t)b * BCAP;
    for (int i = tid; i < cnt; i += 256) {
        u32 w = st[i];
        int l = w >> 17;
        int s = w & 0x1FFFF;
        int p = atomicAdd(&cur[l], 1);
        if ((unsigned)p < (unsigned)NT) col[p] = s;
    }
}

// ---------------- layer 1 fused: GCN agg (pre-scaled bf16 xp) -> LDS -> dense 7->32 + alpha2 ----------------
// 64 nodes/block; 4 lanes/node = 2 edge-slots x 2 chunks. Inner loop: col -> xpb add only.

__global__ void __launch_bounds__(256) k_l1(const u32* __restrict__ xpb,
                                            const int* __restrict__ rowptr,
                                            const int* __restrict__ col,
                                            const float* __restrict__ dinv,
                                            const float* __restrict__ W1,
                                            const float* __restrict__ b1,
                                            const float* __restrict__ va2,
                                            const float* __restrict__ vd2,
                                            u32* __restrict__ O1b,
                                            float* __restrict__ as_,
                                            float* __restrict__ ad_) {
    __shared__ float sW1[7 * 32];
    __shared__ float sb1[32], sva[32], svd[32];
    __shared__ float sT1[64 * 8];
    if (threadIdx.x < 224) sW1[threadIdx.x] = W1[threadIdx.x];
    else {
        int c = threadIdx.x - 224;
        sb1[c] = b1[c]; sva[c] = va2[c]; svd[c] = vd2[c];
    }
    __syncthreads();                 // weights staged; gather/dense are wave-local

    int node_l = threadIdx.x >> 2;
    int lane = threadIdx.x & 3;
    int slot = lane >> 1;            // 2 edge slots
    int ck = lane & 1;               // chunk: words 2ck,2ck+1 -> ch 4ck..4ck+3
    int n = blockIdx.x * 64 + node_l;
    if (n >= NN) return;
    {
        int beg = rowptr[n], end = rowptr[n + 1];
        float a0 = 0.f, a1 = 0.f, a2 = 0.f, a3 = 0.f;
        #pragma unroll 4
        for (int e = beg + slot; e < end; e += 2) {
            int s = clampN(col[e]);
            uint2 u = *(const uint2*)(xpb + (size_t)s * 4 + ck * 2);
            float2 f0 = b2x2(u.x), f1 = b2x2(u.y);
            a0 += f0.x; a1 += f0.y; a2 += f1.x; a3 += f1.y;
        }
        // merge slots (lane ^ 2 within node quad)
        a0 += __shfl_xor(a0, 2, 4); a1 += __shfl_xor(a1, 2, 4);
        a2 += __shfl_xor(a2, 2, 4); a3 += __shfl_xor(a3, 2, 4);
        if (slot == 0) {
            float dn = dinv[n];
            float4 o = {a0 * dn, a1 * dn, a2 * dn, a3 * dn};
            *(float4*)&sT1[node_l * 8 + ck * 4] = o;
        }
    }
    __builtin_amdgcn_wave_barrier();
    int c8 = lane * 8;
    float4 aA = {0,0,0,0}, aB = {0,0,0,0};
    #pragma unroll
    for (int k = 0; k < 7; k++) {
        float t = sT1[node_l * 8 + k];
        float4 wva = *(const float4*)&sW1[k * 32 + c8];
        float4 wvb = *(const float4*)&sW1[k * 32 + c8 + 4];
        FMA4(aA, t, wva);
        FMA4(aB, t, wvb);
    }
    float o0 = fmaxf(aA.x + sb1[c8], 0.f);
    float o1 = fmaxf(aA.y + sb1[c8 + 1], 0.f);
    float o2 = fmaxf(aA.z + sb1[c8 + 2], 0.f);
    float o3 = fmaxf(aA.w + sb1[c8 + 3], 0.f);
    float o4 = fmaxf(aB.x + sb1[c8 + 4], 0.f);
    float o5 = fmaxf(aB.y + sb1[c8 + 5], 0.f);
    float o6 = fmaxf(aB.z + sb1[c8 + 6], 0.f);
    float o7 = fmaxf(aB.w + sb1[c8 + 7], 0.f);
    uint4 pk = {pack2(o0, o1), pack2(o2, o3), pack2(o4, o5), pack2(o6, o7)};
    *(uint4*)(O1b + (size_t)n * 16 + lane * 4) = pk;
    float vs = o0 * sva[c8] + o1 * sva[c8 + 1] + o2 * sva[c8 + 2] + o3 * sva[c8 + 3]
             + o4 * sva[c8 + 4] + o5 * sva[c8 + 5] + o6 * sva[c8 + 6] + o7 * sva[c8 + 7];
    float vd = o0 * svd[c8] + o1 * svd[c8 + 1] + o2 * svd[c8 + 2] + o3 * svd[c8 + 3]
             + o4 * svd[c8 + 4] + o5 * svd[c8 + 5] + o6 * svd[c8 + 6] + o7 * svd[c8 + 7];
    vs += __shfl_xor(vs, 1, 4); vs += __shfl_xor(vs, 2, 4);
    vd += __shfl_xor(vd, 1, 4); vd += __shfl_xor(vd, 2, 4);
    if (lane == 0) { as_[n] = vs; ad_[n] = vd; }
}

// ---------------- layer 2 fused: GAT single-pass agg -> LDS -> dense 32->64 ----------------
// 32 nodes/block; 8 lanes/node = 2 edge-slots x 4 chunks (8 ch each). Wave-synchronous.

__global__ void __launch_bounds__(256) k_l2(const u32* __restrict__ O1b,
                                            const float* __restrict__ as_,
                                            const float* __restrict__ ad_,
                                            const int* __restrict__ rowptr,
                                            const int* __restrict__ col,
                                            const float* __restrict__ W2,
                                            const float* __restrict__ b2,
                                            const float* __restrict__ dinv,
                                            u32* __restrict__ O2b) {
    __shared__ float sW2[32 * 64];    // 8 KB
    __shared__ float sT2[32 * 36];    // stride 36
    __shared__ float sb2[64];
    {
        const float4* g = (const float4*)W2;
        float4* s4 = (float4*)sW2;
        s4[threadIdx.x] = g[threadIdx.x];
        s4[threadIdx.x + 256] = g[threadIdx.x + 256];
    }
    if (threadIdx.x < 64) sb2[threadIdx.x] = b2[threadIdx.x];
    __syncthreads();                 // weights staged; rest is wave-local

    int node_l = threadIdx.x >> 3;
    int l8 = threadIdx.x & 7;
    int slot = l8 >> 2;              // 2 edge slots
    int ck = l8 & 3;                 // chunk: words 4ck..4ck+3 -> ch 8ck..8ck+7
    int n = blockIdx.x * 32 + node_l;            // 3125*32 = NN exact
    {
        int beg = rowptr[n], end = rowptr[n + 1];
        float adn = ad_[n];
        float den = 0.f;
        float a0=0.f,a1=0.f,a2=0.f,a3=0.f,a4=0.f,a5=0.f,a6=0.f,a7=0.f;
        #pragma unroll 4
        for (int e = beg + slot; e < end; e += 2) {
            int s = clampN(col[e]);
            float p = __expf(lrelu_c(as_[s] + adn));
            den += p;
            uint4 w = *(const uint4*)(O1b + (size_t)s * 16 + ck * 4);
            float2 f0 = b2x2(w.x), f1 = b2x2(w.y), f2 = b2x2(w.z), f3 = b2x2(w.w);
            a0 += p * f0.x; a1 += p * f0.y; a2 += p * f1.x; a3 += p * f1.y;
            a4 += p * f2.x; a5 += p * f2.y; a6 += p * f3.x; a7 += p * f3.y;
        }
        // merge slots (lane ^ 4 within node octet)
        den += __shfl_xor(den, 4, 8);
        a0 += __shfl_xor(a0, 4, 8); a1 += __shfl_xor(a1, 4, 8);
        a2 += __shfl_xor(a2, 4, 8); a3 += __shfl_xor(a3, 4, 8);
        a4 += __shfl_xor(a4, 4, 8); a5 += __shfl_xor(a5, 4, 8);
        a6 += __shfl_xor(a6, 4, 8); a7 += __shfl_xor(a7, 4, 8);
        if (slot == 0) {
            float inv = 1.0f / (den + 1e-16f);
            float4 oA = {a0 * inv, a1 * inv, a2 * inv, a3 * inv};
            float4 oB = {a4 * inv, a5 * inv, a6 * inv, a7 * inv};
            float* dst = &sT2[node_l * 36 + ck * 8];
            *(float4*)dst = oA;
            *(float4*)(dst + 4) = oB;
        }
    }
    __builtin_amdgcn_wave_barrier();

    int grp = threadIdx.x >> 4;      // 16 groups
    int l = threadIdx.x & 15;
    int c4 = l * 4;
    int lbase = grp * 2;             // 2 nodes per group

    float4 acc0 = {0,0,0,0}, acc1 = {0,0,0,0};
    #pragma unroll
    for (int k4 = 0; k4 < 8; k4++) {
        float4 t0 = *(const float4*)&sT2[(lbase + 0) * 36 + 4 * k4];
        float4 t1 = *(const float4*)&sT2[(lbase + 1) * 36 + 4 * k4];
        #pragma unroll
        for (int j = 0; j < 4; j++) {
            float4 wv = *(const float4*)&sW2[(4 * k4 + j) * 64 + c4];
            FMA4(acc0, ((const float*)&t0)[j], wv);
            FMA4(acc1, ((const float*)&t1)[j], wv);
        }
    }
    float4 bb = *(const float4*)&sb2[c4];
    int n0 = blockIdx.x * 32 + lbase;
    float d0 = dinv[n0], d1 = dinv[n0 + 1];
    {
        float o0 = fmaxf(acc0.x + bb.x, 0.f) * d0;
        float o1 = fmaxf(acc0.y + bb.y, 0.f) * d0;
        float o2 = fmaxf(acc0.z + bb.z, 0.f) * d0;
        float o3 = fmaxf(acc0.w + bb.w, 0.f) * d0;
        uint2 pk = {pack2(o0, o1), pack2(o2, o3)};
        *(uint2*)(O2b + (size_t)n0 * 32 + l * 2) = pk;
    }
    {
        float o0 = fmaxf(acc1.x + bb.x, 0.f) * d1;
        float o1 = fmaxf(acc1.y + bb.y, 0.f) * d1;
        float o2 = fmaxf(acc1.z + bb.z, 0.f) * d1;
        float o3 = fmaxf(acc1.w + bb.w, 0.f) * d1;
        uint2 pk = {pack2(o0, o1), pack2(o2, o3)};
        *(uint2*)(O2b + (size_t)(n0 + 1) * 32 + l * 2) = pk;
    }
}

// ---------------- layer 3 FUSED: GCN agg over bf16 O2b -> LDS -> W3 -> relu -> W4 ----------------
// R1 structure (best measured): 64 nodes/block, 512 threads, wave-synchronous, sT3 stride 68.

__global__ void __launch_bounds__(512) k_l3(const u32* __restrict__ O2b,
                                            const int* __restrict__ rowptr,
                                            const int* __restrict__ col,
                                            const float* __restrict__ dinv,
                                            const float* __restrict__ W3,
                                            const float* __restrict__ b3,
                                            const float* __restrict__ W4,
                                            const float* __restrict__ av4s,
                                            const float* __restrict__ av4d,
                                            float4* __restrict__ h4as,
                                            float* __restrict__ ad_) {
    __shared__ float sW3[64 * 128];   // 32 KB
    __shared__ float sT3[64 * 68];    // 17 KB, stride 68
    __shared__ float sW4[128 * 2];
    __shared__ float sb3[128];

    {
        const float4* g = (const float4*)W3;
        float4* s4 = (float4*)sW3;
        #pragma unroll
        for (int i = 0; i < 4; i++) s4[threadIdx.x + 512 * i] = g[threadIdx.x + 512 * i];
    }
    if (threadIdx.x < 128) {
        sb3[threadIdx.x] = b3[threadIdx.x];
        sW4[2 * threadIdx.x] = W4[2 * threadIdx.x];
        sW4[2 * threadIdx.x + 1] = W4[2 * threadIdx.x + 1];
    }
    __syncthreads();                  // weights staged; gather/dense are wave-local

    int w = threadIdx.x >> 6;         // wave id 0..7
    int l = threadIdx.x & 63;
    int row = w * 8 + (l >> 3);       // block-local row 0..63
    int cl = l & 7;                   // channel-owner lane
    int n = blockIdx.x * 64 + row;
    if (n >= NN) return;

    // ---- gather: 8 lanes/node, lane cl owns channels cl*8..cl*8+7 ----
    {
        int beg = rowptr[n], end = rowptr[n + 1];
        float4 accA = {0,0,0,0}, accB = {0,0,0,0};
        #pragma unroll 4
        for (int e = beg; e < end; e++) {
            int s = clampN(col[e]);
            uint4 wd = *(const uint4*)(O2b + (size_t)s * 32 + cl * 4);
            float2 f0 = b2x2(wd.x), f1 = b2x2(wd.y), f2 = b2x2(wd.z), f3 = b2x2(wd.w);
            accA.x += f0.x; accA.y += f0.y; accA.z += f1.x; accA.w += f1.y;
            accB.x += f2.x; accB.y += f2.y; accB.z += f3.x; accB.w += f3.y;
        }
        float dn = dinv[n];
        accA.x *= dn; accA.y *= dn; accA.z *= dn; accA.w *= dn;
        accB.x *= dn; accB.y *= dn; accB.z *= dn; accB.w *= dn;
        float* dst = &sT3[row * 68 + cl * 8];
        *(float4*)dst = accA;
        *(float4*)(dst + 4) = accB;
    }
    __builtin_amdgcn_wave_barrier();

    // ---- dense: same wave consumes its own rows; lane cl owns quads {4cl,+32,+64,+96} ----
    const float* trow = &sT3[row * 68];
    float4 acc0 = {0,0,0,0}, acc1 = {0,0,0,0}, acc2 = {0,0,0,0}, acc3 = {0,0,0,0};
    #pragma unroll 4
    for (int k4 = 0; k4 < 16; k4++) {
        float4 t4 = *(const float4*)&trow[k4 * 4];
        #pragma unroll
        for (int j = 0; j < 4; j++) {
            float tj = ((const float*)&t4)[j];
            const float* wr = &sW3[(4 * k4 + j) * 128 + 4 * cl];
            float4 w0 = *(const float4*)&wr[0];
            float4 w1 = *(const float4*)&wr[32];
            float4 w2 = *(const float4*)&wr[64];
            float4 w3v = *(const float4*)&wr[96];
            FMA4(acc0, tj, w0);
            FMA4(acc1, tj, w1);
            FMA4(acc2, tj, w2);
            FMA4(acc3, tj, w3v);
        }
    }

    float av4s0 = av4s[0], av4s1 = av4s[1];
    float av4d0 = av4d[0], av4d1 = av4d[1];
    float p0 = 0.f, p1 = 0.f;
    #pragma unroll
    for (int q = 0; q < 4; q++) {
        float4 a = (q == 0) ? acc0 : (q == 1) ? acc1 : (q == 2) ? acc2 : acc3;
        int c = 4 * cl + 32 * q;
        float4 bb = *(const float4*)&sb3[c];
        a.x = fmaxf(a.x + bb.x, 0.f);
        a.y = fmaxf(a.y + bb.y, 0.f);
        a.z = fmaxf(a.z + bb.z, 0.f);
        a.w = fmaxf(a.w + bb.w, 0.f);
        p0 += a.x * sW4[2 * c]     + a.y * sW4[2 * (c + 1)]
            + a.z * sW4[2 * (c + 2)] + a.w * sW4[2 * (c + 3)];
        p1 += a.x * sW4[2 * c + 1]     + a.y * sW4[2 * (c + 1) + 1]
            + a.z * sW4[2 * (c + 2) + 1] + a.w * sW4[2 * (c + 3) + 1];
    }
    p0 += __shfl_xor(p0, 1, 8); p0 += __shfl_xor(p0, 2, 8); p0 += __shfl_xor(p0, 4, 8);
    p1 += __shfl_xor(p1, 1, 8); p1 += __shfl_xor(p1, 2, 8); p1 += __shfl_xor(p1, 4, 8);
    if (cl == 0) {
        float asv = p0 * av4s0 + p1 * av4s1;
        float4 pk = {p0, p1, asv, 0.f};
        h4as[n] = pk;
        ad_[n] = p0 * av4d0 + p1 * av4d1;
    }
}

// ---------------- final GAT (2ch) + log_softmax, single-pass, 4 lanes/node ----------------

__global__ void k_final(const float4* __restrict__ h4as,
                        const float* __restrict__ ad_, const int* __restrict__ rowptr,
                        const int* __restrict__ col, const float* __restrict__ b,
                        float* __restrict__ out) {
    int gid = blockIdx.x * 256 + threadIdx.x;  // NN*4
    int n = gid >> 2;
    if (n >= NN) return;
    int lsub = gid & 3;
    int beg = rowptr[n], end = rowptr[n + 1];
    float adn = ad_[n];
    float den = 0.f, a0 = 0.f, a1 = 0.f;
    #pragma unroll 2
    for (int e = beg + lsub; e < end; e += 4) {
        int s = clampN(col[e]);
        float4 h = h4as[s];
        float p = __expf(lrelu_c(h.z + adn));
        den += p;
        a0 += p * h.x;
        a1 += p * h.y;
    }
    den += __shfl_xor(den, 1, 4); den += __shfl_xor(den, 2, 4);
    a0  += __shfl_xor(a0, 1, 4);  a0  += __shfl_xor(a0, 2, 4);
    a1  += __shfl_xor(a1, 1, 4);  a1  += __shfl_xor(a1, 2, 4);
    if (lsub == 0) {
        float inv = 1.0f / (den + 1e-16f);
        float v0 = a0 * inv + b[0];
        float v1 = a1 * inv + b[1];
        float mx = fmaxf(v0, v1);
        float lse = mx + logf(__expf(v0 - mx) + __expf(v1 - mx));
        float2 o = {v0 - lse, v1 - lse};
        *(float2*)(out + n * 2) = o;
    }
}

__global__ void k_sentinel(float* __restrict__ out, float v) {
    int i = blockIdx.x * 256 + threadIdx.x;
    if (i < NN * 2) out[i] = v;
}

// ---------------- launch ----------------

extern "C" void kernel_launch(void* const* d_in, const int* in_sizes, int n_in,
                              void* d_out, int out_size, void* d_ws, size_t ws_size,
                              hipStream_t stream) {
    const float* x    = (const float*)d_in[0];
    const int* ei     = (const int*)d_in[1];
    const float* W1   = (const float*)d_in[2];
    const float* b1   = (const float*)d_in[3];
    const float* W2   = (const float*)d_in[4];
    const float* a2s  = (const float*)d_in[5];
    const float* a2d  = (const float*)d_in[6];
    const float* b2   = (const float*)d_in[7];
    const float* W3   = (const float*)d_in[8];
    const float* b3   = (const float*)d_in[9];
    const float* W4   = (const float*)d_in[10];
    const float* a4s  = (const float*)d_in[11];
    const float* a4d  = (const float*)d_in[12];
    const float* b4   = (const float*)d_in[13];
    float* out = (float*)d_out;

    char* base = (char*)d_ws;
    size_t off = 0;
    auto alloc = [&](size_t bytes) {
        char* q = base + off;
        off += (bytes + 255) & ~(size_t)255;
        return q;
    };
    u32* xpb     = (u32*)alloc((size_t)NN * 4 * 4);      // 1.6 MB
    u32* O1b     = (u32*)alloc((size_t)NN * 16 * 4);     // 6.4 MB
    u32* O2b     = (u32*)alloc((size_t)NN * 32 * 4);     // 12.8 MB
    u32* staging = (u32*)alloc((size_t)NBKT * BCAP * 4); // 10.5 MB
    int* col     = (int*)alloc((size_t)NT * 4);          // 6.8 MB
    int* rowptr  = (int*)alloc((size_t)(NN + 1) * 4);
    int* deg     = (int*)alloc((size_t)NN * 4);
    float* dinv  = (float*)alloc((size_t)NN * 4);
    float* as_   = (float*)alloc((size_t)NN * 4);
    float* ad_   = (float*)alloc((size_t)NN * 4);
    float4* h4as = (float4*)alloc((size_t)NN * 16);
    int* part    = (int*)alloc(512 * 4);
    int* flag    = (int*)alloc(256);
    int* gcur    = (int*)alloc(NBKT * 4);
    float* va2   = (float*)alloc(32 * 4);
    float* vd2   = (float*)alloc(32 * 4);

    float code = 0.f;
    if (off > ws_size)            code = 1000.f + (float)(ws_size >> 20);
    else if (n_in != 14)          code = 2000.f + 10.f * (float)n_in;
    else if (out_size != NN * 2)  code = 3400.f;
    if (code != 0.f) {
        k_sentinel<<<(NN * 2 + 255) / 256, 256, 0, stream>>>(out, code);
        return;
    }

    const int NTILE = (NT + 4095) / 4096;

    // CSR build: init -> bin -> hist+localscan(+prescaled xpb pack) -> finalize+scatter
    k_init<<<2, 256, 0, stream>>>(W2, a2s, a2d, ei, va2, vd2, flag, gcur);
    k_binA<<<NTILE, 256, 0, stream>>>(ei, flag, gcur, staging);
    k_histscan<<<NBKT, 256, 0, stream>>>(staging, gcur, x, xpb, rowptr, deg, part);
    k_scat<<<NBKT, 256, 0, stream>>>(staging, gcur, part, rowptr, deg, dinv, col);

    // layer 1 fused: agg(pre-scaled bf16 xp) + dense 7->32 + alpha2
    k_l1<<<(NN + 63) / 64, 256, 0, stream>>>(xpb, rowptr, col, dinv,
                                             W1, b1, va2, vd2, O1b, as_, ad_);
    // layer 2 fused: GAT agg + dense 32->64
    k_l2<<<NN / 32, 256, 0, stream>>>(O1b, as_, ad_, rowptr, col,
                                      W2, b2, dinv, O2b);
    // layer 3 fused: GCN agg + dense 64->128 -> relu -> W4 (R1 best structure)
    k_l3<<<(NN + 63) / 64, 512, 0, stream>>>(O2b, rowptr, col, dinv,
                                             W3, b3, W4, a4s, a4d, h4as, ad_);
    // layer 4 agg + log_softmax
    k_final<<<NN * 4 / 256 + 1, 256, 0, stream>>>(h4as, ad_, rowptr, col, b4, out);
}